// Round 5
// baseline (119.693 us; speedup 1.0000x reference)
//
#include <hip/hip_runtime.h>

typedef unsigned short ushort;
typedef unsigned int uint;
typedef __attribute__((ext_vector_type(8))) short short8;
typedef __attribute__((ext_vector_type(4))) float floatx4;

// Problem constants
#define T_STEPS 100
#define BATCH   32
#define NIN     1024
#define NOUT    512

// K layout: k = b*SEG + t, padded 100 -> 112 (BK-multiple, 16B row alignment)
#define SEG     112
#define KPAD    (BATCH * SEG)          // 3584
#define KROWB   (KPAD * 2)             // 7168 bytes per transposed row
#define KS      16
#define KCHUNK  (KPAD / KS)            // 224
#define BK      32

#define LR_LTP  (1e-4f)
#define LR_LTD  (-1e-4f)
#define INV_B   (1.0f / 32.0f)
#define DECAY   0.951229424500714f     // exp(-1/20)
#define D28     0.246596963941607f     // exp(-28/20)
#define TCH     28                     // t-chunk per thread
#define NCHUNK  4

// Output layout (floats): [delta_w | pre_tr_final | post_tr_final]
#define OFF_PRE  (NOUT * NIN)
#define OFF_POST (OFF_PRE + BATCH * NIN)

// Workspace (ushort elements): 4 transposed bf16 operands [rows][KPAD], then Spart
#define U_PRST  0
#define U_PRTT  (U_PRST + NIN * KPAD)
#define U_POST  (U_PRTT + NIN * KPAD)
#define U_POTT  (U_POST + NOUT * KPAD)
#define U_END   (U_POTT + NOUT * KPAD)   // 11,010,048 ushort = 22 MB

static __device__ __forceinline__ ushort f2bf(float f) {
    union { float f; unsigned int u; } v; v.f = f;
    unsigned int r = (v.u + 0x7FFFu + ((v.u >> 16) & 1u)) >> 16;   // RNE
    return (ushort)r;
}

// ---------------------------------------------------------------------------
// Kernel A: trace recurrence fused with transpose (no LDS tile).
// Block = 64 chains x 4 t-chunks of 28 (t >= 100 zero-padded). Split scan with
// exp(-28/20) carry fixup via tiny LDS array. Each thread then stores its 28
// bf16 spikes + 28 bf16 traces directly into the transposed rows as 7 uint2
// each (8B-aligned). Also writes final fp32 traces to out.
// ---------------------------------------------------------------------------
__global__ __launch_bounds__(256) void stdp_traces_t(
    const float* __restrict__ pre_s,    // [T,B,NIN]
    const float* __restrict__ post_s,   // [T,B,NOUT]
    const float* __restrict__ pre_tr0,  // [B,NIN]
    const float* __restrict__ post_tr0, // [B,NOUT]
    ushort* __restrict__ pre_s_t, ushort* __restrict__ pre_tr_t,
    ushort* __restrict__ post_s_t, ushort* __restrict__ post_tr_t,
    float* __restrict__ out)
{
    __shared__ float Eend[NCHUNK][64];

    const int chain = threadIdx.x & 63;
    const int c     = threadIdx.x >> 6;     // t-chunk, wave-uniform
    const int g     = blockIdx.x * 64 + chain;

    const float* src; const float* init;
    ushort *dstS, *dstT;
    int id, nch, shift, outoff;
    if (g < BATCH * NIN) {
        src = pre_s;  init = pre_tr0;  dstS = pre_s_t;  dstT = pre_tr_t;
        id = g;               nch = NIN;  shift = 10; outoff = OFF_PRE;
    } else {
        src = post_s; init = post_tr0; dstS = post_s_t; dstT = post_tr_t;
        id = g - BATCH * NIN; nch = NOUT; shift = 9;  outoff = OFF_POST;
    }

    const int stride = BATCH * nch;
    const int t0 = c * TCH;

    float x[TCH];
    uint  sp[TCH / 2];
    #pragma unroll
    for (int m = 0; m < TCH; m += 2) {
        float v0 = (t0 + m     < T_STEPS) ? src[(size_t)(t0 + m)     * stride + id] : 0.f;
        float v1 = (t0 + m + 1 < T_STEPS) ? src[(size_t)(t0 + m + 1) * stride + id] : 0.f;
        x[m] = v0; x[m + 1] = v1;
        sp[m / 2] = (uint)f2bf(v0) | ((uint)f2bf(v1) << 16);
    }

    // local scan (zero initial condition)
    float e = 0.f;
    #pragma unroll
    for (int m = 0; m < TCH; ++m) { e = e * DECAY + x[m]; x[m] = e; }
    Eend[c][chain] = e;
    __syncthreads();

    // carry into chunk c
    float C = init[id];
    for (int cc = 0; cc < c; ++cc) C = C * D28 + Eend[cc][chain];
    float p = C * DECAY;
    #pragma unroll
    for (int m = 0; m < TCH; ++m) { x[m] += p; p *= DECAY; }

    if (c == NCHUNK - 1) out[outoff + id] = x[15];   // t = 84 + 15 = 99

    uint tp[TCH / 2];
    #pragma unroll
    for (int m = 0; m < TCH; m += 2)
        tp[m / 2] = (uint)f2bf(x[m]) | ((uint)f2bf(x[m + 1]) << 16);

    const int b  = id >> shift;
    const int ch = id & (nch - 1);
    ushort* ps = dstS + (size_t)ch * KPAD + b * SEG + c * TCH;   // 8B-aligned
    ushort* pt = dstT + (size_t)ch * KPAD + b * SEG + c * TCH;
    #pragma unroll
    for (int j = 0; j < 7; ++j) {
        ((uint2*)ps)[j] = make_uint2(sp[2 * j], sp[2 * j + 1]);
        ((uint2*)pt)[j] = make_uint2(tp[2 * j], tp[2 * j + 1]);
    }
}

// ---------------------------------------------------------------------------
// Kernel B: dual bf16 MFMA GEMM, 128x128 tile, BK=32, 4 waves 2x2,
// global_load_lds w=16, KS=16 K-split (grid 512 = 2 blocks/CU, 7 K-iters).
//   P[o,i] = sum_k post_s[k,o]*pre_tr[k,i]
//   D[o,i] = sum_k post_tr[k,o]*pre_s[k,i]
// Epilogue pre-combines with w:  Spart[z][o,i] = c1*(1-w)*P + c2*w*D
// ---------------------------------------------------------------------------
__global__ __launch_bounds__(256) void stdp_gemm_dual(
    const ushort* __restrict__ post_s_t, const ushort* __restrict__ pre_tr_t,
    const ushort* __restrict__ post_tr_t, const ushort* __restrict__ pre_s_t,
    const float* __restrict__ wmat, float* __restrict__ Spart)
{
    __shared__ ushort AsP[128 * 32];
    __shared__ ushort AsD[128 * 32];
    __shared__ ushort BsP[128 * 32];
    __shared__ ushort BsD[128 * 32];

    const int i0 = blockIdx.x * 128;
    const int o0 = blockIdx.y * 128;
    const int k0 = blockIdx.z * KCHUNK;

    const int tid  = threadIdx.x;
    const int w    = tid >> 6;
    const int lane = tid & 63;
    const int quad = lane >> 4;
    const int l16  = lane & 15;
    const int wm   = w & 1;
    const int wn   = w >> 1;

    floatx4 accP[4][4], accD[4][4];
    const floatx4 zero4 = {0.f, 0.f, 0.f, 0.f};
    #pragma unroll
    for (int mt = 0; mt < 4; ++mt)
        #pragma unroll
        for (int nt = 0; nt < 4; ++nt) { accP[mt][nt] = zero4; accD[mt][nt] = zero4; }

    for (int kb = k0; kb < k0 + KCHUNK; kb += BK) {
        #pragma unroll
        for (int q = 0; q < 2; ++q) {
            const int c   = w * 128 + q * 64 + lane;   // 16B chunk 0..511
            const int row = c >> 2;
            const int kob = (c & 3) * 16;
            const size_t aoff = (size_t)(o0 + row) * KROWB + kb * 2 + kob;
            const size_t boff = (size_t)(i0 + row) * KROWB + kb * 2 + kob;
            const int ldso = w * 2048 + q * 1024;
            __builtin_amdgcn_global_load_lds(
                (const __attribute__((address_space(1))) void*)((const char*)post_s_t + aoff),
                (__attribute__((address_space(3))) void*)((char*)AsP + ldso), 16, 0, 0);
            __builtin_amdgcn_global_load_lds(
                (const __attribute__((address_space(1))) void*)((const char*)post_tr_t + aoff),
                (__attribute__((address_space(3))) void*)((char*)AsD + ldso), 16, 0, 0);
            __builtin_amdgcn_global_load_lds(
                (const __attribute__((address_space(1))) void*)((const char*)pre_tr_t + boff),
                (__attribute__((address_space(3))) void*)((char*)BsP + ldso), 16, 0, 0);
            __builtin_amdgcn_global_load_lds(
                (const __attribute__((address_space(1))) void*)((const char*)pre_s_t + boff),
                (__attribute__((address_space(3))) void*)((char*)BsD + ldso), 16, 0, 0);
        }
        __syncthreads();

        short8 aP[4], aD[4], bP[4], bD[4];
        #pragma unroll
        for (int mt = 0; mt < 4; ++mt) {
            const int r = (wm * 64 + mt * 16 + l16) * 32 + quad * 8;
            aP[mt] = *(const short8*)&AsP[r];
            aD[mt] = *(const short8*)&AsD[r];
        }
        #pragma unroll
        for (int nt = 0; nt < 4; ++nt) {
            const int r = (wn * 64 + nt * 16 + l16) * 32 + quad * 8;
            bP[nt] = *(const short8*)&BsP[r];
            bD[nt] = *(const short8*)&BsD[r];
        }
        #pragma unroll
        for (int mt = 0; mt < 4; ++mt)
            #pragma unroll
            for (int nt = 0; nt < 4; ++nt) {
                accP[mt][nt] = __builtin_amdgcn_mfma_f32_16x16x32_bf16(
                    aP[mt], bP[nt], accP[mt][nt], 0, 0, 0);
                accD[mt][nt] = __builtin_amdgcn_mfma_f32_16x16x32_bf16(
                    aD[mt], bD[nt], accD[mt][nt], 0, 0, 0);
            }
        __syncthreads();
    }

    // epilogue: C/D layout col = lane&15 (i), row = quad*4+reg (o)
    float* Sz = Spart + (size_t)blockIdx.z * (NOUT * NIN);
    const float c1 = LR_LTP * INV_B;
    const float c2 = LR_LTD * INV_B;
    #pragma unroll
    for (int mt = 0; mt < 4; ++mt) {
        const int obase = o0 + wm * 64 + mt * 16 + quad * 4;
        #pragma unroll
        for (int nt = 0; nt < 4; ++nt) {
            const int i = i0 + wn * 64 + nt * 16 + l16;
            #pragma unroll
            for (int r = 0; r < 4; ++r) {
                const size_t idx = (size_t)(obase + r) * NIN + i;
                const float wv = wmat[idx];
                Sz[idx] = c1 * (1.0f - wv) * accP[mt][nt][r]
                        + c2 * wv          * accD[mt][nt][r];
            }
        }
    }
}

// ---------------------------------------------------------------------------
// Kernel C: sum the KS pre-combined slabs -> dw
// ---------------------------------------------------------------------------
__global__ __launch_bounds__(256) void stdp_finalize(
    const float* __restrict__ Spart, float* __restrict__ out)
{
    const int j = blockIdx.x * blockDim.x + threadIdx.x;   // float4 index
    float4 s = make_float4(0.f, 0.f, 0.f, 0.f);
    #pragma unroll
    for (int z = 0; z < KS; ++z) {
        const float4 p = ((const float4*)(Spart + (size_t)z * (NOUT * NIN)))[j];
        s.x += p.x; s.y += p.y; s.z += p.z; s.w += p.w;
    }
    ((float4*)out)[j] = s;
}

extern "C" void kernel_launch(void* const* d_in, const int* in_sizes, int n_in,
                              void* d_out, int out_size, void* d_ws, size_t ws_size,
                              hipStream_t stream) {
    const float* weight   = (const float*)d_in[0];
    const float* pre_s    = (const float*)d_in[1];
    const float* post_s   = (const float*)d_in[2];
    const float* pre_tr0  = (const float*)d_in[3];
    const float* post_tr0 = (const float*)d_in[4];
    float* out = (float*)d_out;

    ushort* u = (ushort*)d_ws;
    ushort* pre_s_t   = u + U_PRST;
    ushort* pre_tr_t  = u + U_PRTT;
    ushort* post_s_t  = u + U_POST;
    ushort* post_tr_t = u + U_POTT;
    float*  Spart     = (float*)((char*)d_ws + (size_t)U_END * 2);

    stdp_traces_t<<<dim3(BATCH * (NIN + NOUT) / 64), dim3(256), 0, stream>>>(
        pre_s, post_s, pre_tr0, post_tr0,
        pre_s_t, pre_tr_t, post_s_t, post_tr_t, out);

    stdp_gemm_dual<<<dim3(NIN / 128, NOUT / 128, KS), dim3(256), 0, stream>>>(
        post_s_t, pre_tr_t, post_tr_t, pre_s_t, weight, Spart);

    stdp_finalize<<<dim3((NOUT * NIN / 4) / 256), dim3(256), 0, stream>>>(
        Spart, out);
}

// Round 6
// 114.478 us; speedup vs baseline: 1.0456x; 1.0456x over previous
//
#include <hip/hip_runtime.h>

typedef unsigned short ushort;
typedef unsigned int uint;
typedef __attribute__((ext_vector_type(8))) short short8;
typedef __attribute__((ext_vector_type(4))) float floatx4;

// Problem constants
#define T_STEPS 100
#define BATCH   32
#define NIN     1024
#define NOUT    512

// K layout: k = b*SEG + t, t padded 100 -> 112. K extent KPAD = 3584.
// Row STRIDE is 3648 ushort = 7296 B = 28.5 x 256B -> consecutive rows rotate
// across L2 channels (stride 7168 = 28x256 in R5 aliased to 1/4 of channels).
#define SEG     112
#define KPAD    (BATCH * SEG)          // 3584 (GEMM K extent)
#define KSTRIDE 3648                   // ushort row stride
#define KROWB   (KSTRIDE * 2)          // 7296 bytes
#define KS      16
#define KCHUNK  (KPAD / KS)            // 224
#define BK      32

#define LR_LTP  (1e-4f)
#define LR_LTD  (-1e-4f)
#define INV_B   (1.0f / 32.0f)
#define DECAY   0.951229424500714f     // exp(-1/20)
#define D28     0.246596963941607f     // exp(-28/20)
#define TCH     28                     // t-chunk per thread
#define NCHUNK  4
#define LROW    120                    // LDS row stride in ushort (240 B)

// Output layout (floats): [delta_w | pre_tr_final | post_tr_final]
#define OFF_PRE  (NOUT * NIN)
#define OFF_POST (OFF_PRE + BATCH * NIN)

// Workspace (ushort elements): 4 transposed bf16 operands [rows][KSTRIDE]
#define U_PRST  0
#define U_PRTT  (U_PRST + NIN * KSTRIDE)
#define U_POST  (U_PRTT + NIN * KSTRIDE)
#define U_POTT  (U_POST + NOUT * KSTRIDE)
#define U_END   (U_POTT + NOUT * KSTRIDE)
// Spart slabs: NOUT*NIN + 64 floats (stride 8193 x 256B -> full channel spread)
#define SLABF   (NOUT * NIN + 64)

static __device__ __forceinline__ ushort f2bf(float f) {
    union { float f; unsigned int u; } v; v.f = f;
    unsigned int r = (v.u + 0x7FFFu + ((v.u >> 16) & 1u)) >> 16;   // RNE
    return (ushort)r;
}

// ---------------------------------------------------------------------------
// Kernel A: trace recurrence fused with transpose, LDS-assembled writes.
// Block = 64 chains x 4 t-chunks of 28 (t >= 100: spikes zero-padded).
// Split scan with exp(-28/20) carry fixup. Results staged in LDS
// [64][LROW] per operand, then written out as 16B chunks with consecutive
// lanes on consecutive chunks (coalesced, ~5 line-txns/instr).
// ---------------------------------------------------------------------------
__global__ __launch_bounds__(256) void stdp_traces_t(
    const float* __restrict__ pre_s,    // [T,B,NIN]
    const float* __restrict__ post_s,   // [T,B,NOUT]
    const float* __restrict__ pre_tr0,  // [B,NIN]
    const float* __restrict__ post_tr0, // [B,NOUT]
    ushort* __restrict__ pre_s_t, ushort* __restrict__ pre_tr_t,
    ushort* __restrict__ post_s_t, ushort* __restrict__ post_tr_t,
    float* __restrict__ out)
{
    __shared__ __align__(16) ushort Ls[64 * LROW];   // spikes, 15 KB
    __shared__ __align__(16) ushort Lt[64 * LROW];   // traces, 15 KB
    __shared__ float Eend[NCHUNK][64];

    const int chain = threadIdx.x & 63;
    const int c     = threadIdx.x >> 6;     // t-chunk, wave-uniform
    const int g     = blockIdx.x * 64 + chain;

    const float* src; const float* init;
    int id, stride, outoff;
    if (g < BATCH * NIN) {
        src = pre_s;  init = pre_tr0;
        id = g;               stride = BATCH * NIN;  outoff = OFF_PRE;
    } else {
        src = post_s; init = post_tr0;
        id = g - BATCH * NIN; stride = BATCH * NOUT; outoff = OFF_POST;
    }

    const int t0 = c * TCH;
    float x[TCH];
    uint  sp[TCH / 2];
    #pragma unroll
    for (int m = 0; m < TCH; m += 2) {
        float v0 = (t0 + m     < T_STEPS) ? src[(size_t)(t0 + m)     * stride + id] : 0.f;
        float v1 = (t0 + m + 1 < T_STEPS) ? src[(size_t)(t0 + m + 1) * stride + id] : 0.f;
        x[m] = v0; x[m + 1] = v1;
        sp[m / 2] = (uint)f2bf(v0) | ((uint)f2bf(v1) << 16);
    }

    // local scan (zero initial condition)
    float e = 0.f;
    #pragma unroll
    for (int m = 0; m < TCH; ++m) { e = e * DECAY + x[m]; x[m] = e; }
    Eend[c][chain] = e;
    __syncthreads();

    // carry into chunk c
    float C = init[id];
    for (int cc = 0; cc < c; ++cc) C = C * D28 + Eend[cc][chain];
    float p = C * DECAY;
    #pragma unroll
    for (int m = 0; m < TCH; ++m) { x[m] += p; p *= DECAY; }

    if (c == NCHUNK - 1) out[outoff + id] = x[15];   // t = 84 + 15 = 99

    // stage into LDS: [chain][c*28 .. +28), 7 x 8B per operand
    {
        ushort* ls = Ls + chain * LROW + c * TCH;
        ushort* lt = Lt + chain * LROW + c * TCH;
        #pragma unroll
        for (int j = 0; j < 7; ++j) {
            const float x0 = x[2 * j * 2];   // dummy to keep order; not used
            (void)x0;
            ((uint2*)ls)[j] = make_uint2(sp[2 * j], sp[2 * j + 1]);
            const uint t_lo = (uint)f2bf(x[4 * j])     | ((uint)f2bf(x[4 * j + 1]) << 16);
            const uint t_hi = (uint)f2bf(x[4 * j + 2]) | ((uint)f2bf(x[4 * j + 3]) << 16);
            ((uint2*)lt)[j] = make_uint2(t_lo, t_hi);
        }
    }
    __syncthreads();

    // cooperative coalesced write-out: 2 operands x 64 rows x 14 16B-chunks
    int id0 = blockIdx.x * 64;
    ushort *dS, *dT; int b0, ch0;
    if (id0 < BATCH * NIN) {
        b0 = id0 >> 10; ch0 = id0 & 1023; dS = pre_s_t;  dT = pre_tr_t;
    } else {
        const int idq = id0 - BATCH * NIN;
        b0 = idq >> 9;  ch0 = idq & 511;  dS = post_s_t; dT = post_tr_t;
    }
    #pragma unroll
    for (int j = 0; j < 7; ++j) {
        const int q  = threadIdx.x + 256 * j;   // 0..1791
        const int op = q >= 896;
        const int qq = q - op * 896;
        const int r  = qq / 14;                 // 0..63
        const int cc = qq - r * 14;             // 0..13
        const ushort* lsrc = (op ? Lt : Ls) + r * LROW + cc * 8;
        ushort* gdst = (op ? dT : dS) + (size_t)(ch0 + r) * KSTRIDE + b0 * SEG + cc * 8;
        *(uint4*)gdst = *(const uint4*)lsrc;
    }
}

// ---------------------------------------------------------------------------
// Kernel B: dual bf16 MFMA GEMM, 128x128 tile, BK=32, 4 waves 2x2,
// global_load_lds w=16, KS=16 K-split (512 blocks = 2/CU, 7 K-iters).
//   P[o,i] = sum_k post_s[k,o]*pre_tr[k,i]
//   D[o,i] = sum_k post_tr[k,o]*pre_s[k,i]
// Epilogue pre-combines with w:  Spart[z][o,i] = c1*(1-w)*P + c2*w*D
// ---------------------------------------------------------------------------
__global__ __launch_bounds__(256) void stdp_gemm_dual(
    const ushort* __restrict__ post_s_t, const ushort* __restrict__ pre_tr_t,
    const ushort* __restrict__ post_tr_t, const ushort* __restrict__ pre_s_t,
    const float* __restrict__ wmat, float* __restrict__ Spart)
{
    __shared__ ushort AsP[128 * 32];
    __shared__ ushort AsD[128 * 32];
    __shared__ ushort BsP[128 * 32];
    __shared__ ushort BsD[128 * 32];

    const int i0 = blockIdx.x * 128;
    const int o0 = blockIdx.y * 128;
    const int k0 = blockIdx.z * KCHUNK;

    const int tid  = threadIdx.x;
    const int w    = tid >> 6;
    const int lane = tid & 63;
    const int quad = lane >> 4;
    const int l16  = lane & 15;
    const int wm   = w & 1;
    const int wn   = w >> 1;

    floatx4 accP[4][4], accD[4][4];
    const floatx4 zero4 = {0.f, 0.f, 0.f, 0.f};
    #pragma unroll
    for (int mt = 0; mt < 4; ++mt)
        #pragma unroll
        for (int nt = 0; nt < 4; ++nt) { accP[mt][nt] = zero4; accD[mt][nt] = zero4; }

    for (int kb = k0; kb < k0 + KCHUNK; kb += BK) {
        #pragma unroll
        for (int q = 0; q < 2; ++q) {
            const int c   = w * 128 + q * 64 + lane;   // 16B chunk 0..511
            const int row = c >> 2;
            const int kob = (c & 3) * 16;
            const size_t aoff = (size_t)(o0 + row) * KROWB + kb * 2 + kob;
            const size_t boff = (size_t)(i0 + row) * KROWB + kb * 2 + kob;
            const int ldso = w * 2048 + q * 1024;
            __builtin_amdgcn_global_load_lds(
                (const __attribute__((address_space(1))) void*)((const char*)post_s_t + aoff),
                (__attribute__((address_space(3))) void*)((char*)AsP + ldso), 16, 0, 0);
            __builtin_amdgcn_global_load_lds(
                (const __attribute__((address_space(1))) void*)((const char*)post_tr_t + aoff),
                (__attribute__((address_space(3))) void*)((char*)AsD + ldso), 16, 0, 0);
            __builtin_amdgcn_global_load_lds(
                (const __attribute__((address_space(1))) void*)((const char*)pre_tr_t + boff),
                (__attribute__((address_space(3))) void*)((char*)BsP + ldso), 16, 0, 0);
            __builtin_amdgcn_global_load_lds(
                (const __attribute__((address_space(1))) void*)((const char*)pre_s_t + boff),
                (__attribute__((address_space(3))) void*)((char*)BsD + ldso), 16, 0, 0);
        }
        __syncthreads();

        short8 aP[4], aD[4], bP[4], bD[4];
        #pragma unroll
        for (int mt = 0; mt < 4; ++mt) {
            const int r = (wm * 64 + mt * 16 + l16) * 32 + quad * 8;
            aP[mt] = *(const short8*)&AsP[r];
            aD[mt] = *(const short8*)&AsD[r];
        }
        #pragma unroll
        for (int nt = 0; nt < 4; ++nt) {
            const int r = (wn * 64 + nt * 16 + l16) * 32 + quad * 8;
            bP[nt] = *(const short8*)&BsP[r];
            bD[nt] = *(const short8*)&BsD[r];
        }
        #pragma unroll
        for (int mt = 0; mt < 4; ++mt)
            #pragma unroll
            for (int nt = 0; nt < 4; ++nt) {
                accP[mt][nt] = __builtin_amdgcn_mfma_f32_16x16x32_bf16(
                    aP[mt], bP[nt], accP[mt][nt], 0, 0, 0);
                accD[mt][nt] = __builtin_amdgcn_mfma_f32_16x16x32_bf16(
                    aD[mt], bD[nt], accD[mt][nt], 0, 0, 0);
            }
        __syncthreads();
    }

    // epilogue: C/D layout col = lane&15 (i), row = quad*4+reg (o)
    float* Sz = Spart + (size_t)blockIdx.z * SLABF;
    const float c1 = LR_LTP * INV_B;
    const float c2 = LR_LTD * INV_B;
    #pragma unroll
    for (int mt = 0; mt < 4; ++mt) {
        const int obase = o0 + wm * 64 + mt * 16 + quad * 4;
        #pragma unroll
        for (int nt = 0; nt < 4; ++nt) {
            const int i = i0 + wn * 64 + nt * 16 + l16;
            #pragma unroll
            for (int r = 0; r < 4; ++r) {
                const size_t idx = (size_t)(obase + r) * NIN + i;
                const float wv = wmat[idx];
                Sz[idx] = c1 * (1.0f - wv) * accP[mt][nt][r]
                        + c2 * wv          * accD[mt][nt][r];
            }
        }
    }
}

// ---------------------------------------------------------------------------
// Kernel C: sum the KS pre-combined slabs -> dw
// ---------------------------------------------------------------------------
__global__ __launch_bounds__(256) void stdp_finalize(
    const float* __restrict__ Spart, float* __restrict__ out)
{
    const int j = blockIdx.x * blockDim.x + threadIdx.x;   // float4 index
    float4 s = make_float4(0.f, 0.f, 0.f, 0.f);
    #pragma unroll
    for (int z = 0; z < KS; ++z) {
        const float4 p = ((const float4*)(Spart + (size_t)z * SLABF))[j];
        s.x += p.x; s.y += p.y; s.z += p.z; s.w += p.w;
    }
    ((float4*)out)[j] = s;
}

extern "C" void kernel_launch(void* const* d_in, const int* in_sizes, int n_in,
                              void* d_out, int out_size, void* d_ws, size_t ws_size,
                              hipStream_t stream) {
    const float* weight   = (const float*)d_in[0];
    const float* pre_s    = (const float*)d_in[1];
    const float* post_s   = (const float*)d_in[2];
    const float* pre_tr0  = (const float*)d_in[3];
    const float* post_tr0 = (const float*)d_in[4];
    float* out = (float*)d_out;

    ushort* u = (ushort*)d_ws;
    ushort* pre_s_t   = u + U_PRST;
    ushort* pre_tr_t  = u + U_PRTT;
    ushort* post_s_t  = u + U_POST;
    ushort* post_tr_t = u + U_POTT;
    float*  Spart     = (float*)((char*)d_ws + (size_t)U_END * 2);

    stdp_traces_t<<<dim3(BATCH * (NIN + NOUT) / 64), dim3(256), 0, stream>>>(
        pre_s, post_s, pre_tr0, post_tr0,
        pre_s_t, pre_tr_t, post_s_t, post_tr_t, out);

    stdp_gemm_dual<<<dim3(NIN / 128, NOUT / 128, KS), dim3(256), 0, stream>>>(
        post_s_t, pre_tr_t, post_tr_t, pre_s_t, weight, Spart);

    stdp_finalize<<<dim3((NOUT * NIN / 4) / 256), dim3(256), 0, stream>>>(
        Spart, out);
}

// Round 7
// 103.166 us; speedup vs baseline: 1.1602x; 1.1096x over previous
//
#include <hip/hip_runtime.h>

typedef unsigned short ushort;
typedef unsigned int uint;
typedef unsigned char uchar;
typedef long long i64;
typedef __attribute__((ext_vector_type(4))) float floatx4;

// Problem constants
#define T_STEPS 100
#define BATCH   32
#define NIN     1024
#define NOUT    512

// K layout: k = b*SEG + t, t padded 100 -> 112. Operands stored fp8 e4m3,
// [rows][K], row stride 3648 B = 14.25 x 256B (rotates L2 channels).
#define SEG      112
#define KPAD     (BATCH * SEG)         // 3584 (GEMM K extent, bytes = elems)
#define KSTRIDEB 3648                  // row stride in bytes
#define KS       16
#define KCHUNK   (KPAD / KS)           // 224
#define BK       32

#define LR_LTP  (1e-4f)
#define LR_LTD  (-1e-4f)
#define INV_B   (1.0f / 32.0f)
#define DECAY   0.951229424500714f     // exp(-1/20)
#define D28     0.246596963941607f     // exp(-28/20)
#define TCH     28                     // t-chunk per thread
#define NCHUNK  4

// Output layout (floats): [delta_w | pre_tr_final | post_tr_final]
#define OFF_PRE  (NOUT * NIN)
#define OFF_POST (OFF_PRE + BATCH * NIN)

// Workspace (bytes): 4 fp8 operands, then fp32 Spart slabs
#define B_PRST  0
#define B_PRTT  ((size_t)NIN * KSTRIDEB)
#define B_POST  ((size_t)2 * NIN * KSTRIDEB)
#define B_POTT  ((size_t)2 * NIN * KSTRIDEB + (size_t)NOUT * KSTRIDEB)
#define B_END   ((size_t)2 * (NIN + NOUT) * KSTRIDEB)   // 11,206,656 B
// Spart slab stride: NOUT*NIN + 64 floats = 8193 x 256B (full channel spread)
#define SLABF   (NOUT * NIN + 64)

static __device__ __forceinline__ uint pk4_fp8(float a, float b, float c, float d) {
    uint v = 0;
    v = __builtin_amdgcn_cvt_pk_fp8_f32(a, b, v, false);   // low 16 bits
    v = __builtin_amdgcn_cvt_pk_fp8_f32(c, d, v, true);    // high 16 bits
    return v;
}

// ---------------------------------------------------------------------------
// Kernel A: trace recurrence fused with transpose, fp8 e4m3 outputs.
// Block = 64 chains x 4 t-chunks of 28 (t >= 100: spikes zero-padded; pad
// traces decay on but are always multiplied by zero spikes in the GEMM).
// Split scan with exp(-28/20) carry fixup. fp8-packed results staged in LDS
// rows of 33 words (banks spread: (33*chain+w) % 32 -> 2-way max), then
// written out cooperatively as 16B chunks. Final fp32 traces -> out.
// ---------------------------------------------------------------------------
__global__ __launch_bounds__(256) void stdp_traces_t(
    const float* __restrict__ pre_s,    // [T,B,NIN]
    const float* __restrict__ post_s,   // [T,B,NOUT]
    const float* __restrict__ pre_tr0,  // [B,NIN]
    const float* __restrict__ post_tr0, // [B,NOUT]
    uchar* __restrict__ pre_s_t, uchar* __restrict__ pre_tr_t,
    uchar* __restrict__ post_s_t, uchar* __restrict__ post_tr_t,
    float* __restrict__ out)
{
    __shared__ uint Ls[64 * 33];   // packed fp8 spikes, 8.25 KB
    __shared__ uint Lt[64 * 33];   // packed fp8 traces
    __shared__ float Eend[NCHUNK][64];

    const int chain = threadIdx.x & 63;
    const int c     = threadIdx.x >> 6;     // t-chunk, wave-uniform
    const int g     = blockIdx.x * 64 + chain;

    const float* src; const float* init;
    int id, stride, outoff;
    if (g < BATCH * NIN) {
        src = pre_s;  init = pre_tr0;
        id = g;               stride = BATCH * NIN;  outoff = OFF_PRE;
    } else {
        src = post_s; init = post_tr0;
        id = g - BATCH * NIN; stride = BATCH * NOUT; outoff = OFF_POST;
    }

    const int t0 = c * TCH;
    float x[TCH];
    #pragma unroll
    for (int m = 0; m < TCH; ++m)
        x[m] = (t0 + m < T_STEPS) ? src[(size_t)(t0 + m) * stride + id] : 0.f;

    // pack spikes to fp8 before the scan overwrites x[]
    uint sp[7];
    #pragma unroll
    for (int j = 0; j < 7; ++j)
        sp[j] = pk4_fp8(x[4*j], x[4*j+1], x[4*j+2], x[4*j+3]);

    // local scan (zero initial condition)
    float e = 0.f;
    #pragma unroll
    for (int m = 0; m < TCH; ++m) { e = e * DECAY + x[m]; x[m] = e; }
    Eend[c][chain] = e;
    __syncthreads();

    // carry into chunk c
    float C = init[id];
    for (int cc = 0; cc < c; ++cc) C = C * D28 + Eend[cc][chain];
    float p = C * DECAY;
    #pragma unroll
    for (int m = 0; m < TCH; ++m) { x[m] += p; p *= DECAY; }

    if (c == NCHUNK - 1) out[outoff + id] = x[15];   // t = 84 + 15 = 99

    // stage packed fp8 into LDS
    #pragma unroll
    for (int j = 0; j < 7; ++j) {
        const uint tj = pk4_fp8(x[4*j], x[4*j+1], x[4*j+2], x[4*j+3]);
        Ls[chain * 33 + c * 7 + j] = sp[j];
        Lt[chain * 33 + c * 7 + j] = tj;
    }
    __syncthreads();

    // cooperative coalesced write-out: 2 ops x 64 rows x 7 16B-chunks = 896
    const int id0 = blockIdx.x * 64;
    uchar *dS, *dT; int b0, ch0;
    if (id0 < BATCH * NIN) {
        b0 = id0 >> 10; ch0 = id0 & 1023; dS = pre_s_t;  dT = pre_tr_t;
    } else {
        const int idq = id0 - BATCH * NIN;
        b0 = idq >> 9;  ch0 = idq & 511;  dS = post_s_t; dT = post_tr_t;
    }
    #pragma unroll
    for (int j = 0; j < 4; ++j) {
        const int q = threadIdx.x + 256 * j;
        if (q < 896) {
            const int op = q >= 448;
            const int qq = q - op * 448;
            const int r  = qq / 7;
            const int cc = qq - r * 7;
            const uint* l = (op ? Lt : Ls) + r * 33 + cc * 4;
            const uint4 v = make_uint4(l[0], l[1], l[2], l[3]);
            uchar* gd = (op ? dT : dS) + (size_t)(ch0 + r) * KSTRIDEB + b0 * SEG + cc * 16;
            *(uint4*)gd = v;
        }
    }
}

// ---------------------------------------------------------------------------
// Kernel B: dual fp8 MFMA GEMM, 128x128 tile, BK=32, 4 waves 2x2,
// global_load_lds w=16, KS=16 K-split (512 blocks = 2/CU, 7 K-iters).
//   P[o,i] = sum_k post_s[k,o]*pre_tr[k,i]
//   D[o,i] = sum_k post_tr[k,o]*pre_s[k,i]
// Epilogue pre-combines with w:  Spart[z][o,i] = c1*(1-w)*P + c2*w*D
// ---------------------------------------------------------------------------
__global__ __launch_bounds__(256) void stdp_gemm_dual(
    const uchar* __restrict__ post_s_t, const uchar* __restrict__ pre_tr_t,
    const uchar* __restrict__ post_tr_t, const uchar* __restrict__ pre_s_t,
    const float* __restrict__ wmat, float* __restrict__ Spart)
{
    __shared__ uchar AsP[128 * 32];   // 4 KB each
    __shared__ uchar AsD[128 * 32];
    __shared__ uchar BsP[128 * 32];
    __shared__ uchar BsD[128 * 32];

    const int i0 = blockIdx.x * 128;
    const int o0 = blockIdx.y * 128;
    const int k0 = blockIdx.z * KCHUNK;

    const int tid  = threadIdx.x;
    const int w    = tid >> 6;
    const int lane = tid & 63;
    const int quad = lane >> 4;
    const int l16  = lane & 15;
    const int wm   = w & 1;
    const int wn   = w >> 1;

    floatx4 accP[4][4], accD[4][4];
    const floatx4 zero4 = {0.f, 0.f, 0.f, 0.f};
    #pragma unroll
    for (int mt = 0; mt < 4; ++mt)
        #pragma unroll
        for (int nt = 0; nt < 4; ++nt) { accP[mt][nt] = zero4; accD[mt][nt] = zero4; }

    for (int kb = k0; kb < k0 + KCHUNK; kb += BK) {
        // one 16B chunk per thread per operand: 256 chunks cover 128x32B
        {
            const int c   = w * 64 + lane;      // 0..255
            const int row = c >> 1;
            const int kob = (c & 1) * 16;
            const size_t aoff = (size_t)(o0 + row) * KSTRIDEB + kb + kob;
            const size_t boff = (size_t)(i0 + row) * KSTRIDEB + kb + kob;
            const int ldso = w * 1024;
            __builtin_amdgcn_global_load_lds(
                (const __attribute__((address_space(1))) void*)(post_s_t + aoff),
                (__attribute__((address_space(3))) void*)((char*)AsP + ldso), 16, 0, 0);
            __builtin_amdgcn_global_load_lds(
                (const __attribute__((address_space(1))) void*)(post_tr_t + aoff),
                (__attribute__((address_space(3))) void*)((char*)AsD + ldso), 16, 0, 0);
            __builtin_amdgcn_global_load_lds(
                (const __attribute__((address_space(1))) void*)(pre_tr_t + boff),
                (__attribute__((address_space(3))) void*)((char*)BsP + ldso), 16, 0, 0);
            __builtin_amdgcn_global_load_lds(
                (const __attribute__((address_space(1))) void*)(pre_s_t + boff),
                (__attribute__((address_space(3))) void*)((char*)BsD + ldso), 16, 0, 0);
        }
        __syncthreads();

        i64 aP[4], aD[4], bP[4], bD[4];
        #pragma unroll
        for (int mt = 0; mt < 4; ++mt) {
            const int r = (wm * 64 + mt * 16 + l16) * 32 + quad * 8;
            aP[mt] = *(const i64*)&AsP[r];
            aD[mt] = *(const i64*)&AsD[r];
        }
        #pragma unroll
        for (int nt = 0; nt < 4; ++nt) {
            const int r = (wn * 64 + nt * 16 + l16) * 32 + quad * 8;
            bP[nt] = *(const i64*)&BsP[r];
            bD[nt] = *(const i64*)&BsD[r];
        }
        #pragma unroll
        for (int mt = 0; mt < 4; ++mt)
            #pragma unroll
            for (int nt = 0; nt < 4; ++nt) {
                accP[mt][nt] = __builtin_amdgcn_mfma_f32_16x16x32_fp8_fp8(
                    aP[mt], bP[nt], accP[mt][nt], 0, 0, 0);
                accD[mt][nt] = __builtin_amdgcn_mfma_f32_16x16x32_fp8_fp8(
                    aD[mt], bD[nt], accD[mt][nt], 0, 0, 0);
            }
        __syncthreads();
    }

    // epilogue: C/D layout col = lane&15 (i), row = quad*4+reg (o)
    float* Sz = Spart + (size_t)blockIdx.z * SLABF;
    const float c1 = LR_LTP * INV_B;
    const float c2 = LR_LTD * INV_B;
    #pragma unroll
    for (int mt = 0; mt < 4; ++mt) {
        const int obase = o0 + wm * 64 + mt * 16 + quad * 4;
        #pragma unroll
        for (int nt = 0; nt < 4; ++nt) {
            const int i = i0 + wn * 64 + nt * 16 + l16;
            #pragma unroll
            for (int r = 0; r < 4; ++r) {
                const size_t idx = (size_t)(obase + r) * NIN + i;
                const float wv = wmat[idx];
                Sz[idx] = c1 * (1.0f - wv) * accP[mt][nt][r]
                        + c2 * wv          * accD[mt][nt][r];
            }
        }
    }
}

// ---------------------------------------------------------------------------
// Kernel C: sum the KS pre-combined slabs -> dw
// ---------------------------------------------------------------------------
__global__ __launch_bounds__(256) void stdp_finalize(
    const float* __restrict__ Spart, float* __restrict__ out)
{
    const int j = blockIdx.x * blockDim.x + threadIdx.x;   // float4 index
    float4 s = make_float4(0.f, 0.f, 0.f, 0.f);
    #pragma unroll
    for (int z = 0; z < KS; ++z) {
        const float4 p = ((const float4*)(Spart + (size_t)z * SLABF))[j];
        s.x += p.x; s.y += p.y; s.z += p.z; s.w += p.w;
    }
    ((float4*)out)[j] = s;
}

extern "C" void kernel_launch(void* const* d_in, const int* in_sizes, int n_in,
                              void* d_out, int out_size, void* d_ws, size_t ws_size,
                              hipStream_t stream) {
    const float* weight   = (const float*)d_in[0];
    const float* pre_s    = (const float*)d_in[1];
    const float* post_s   = (const float*)d_in[2];
    const float* pre_tr0  = (const float*)d_in[3];
    const float* post_tr0 = (const float*)d_in[4];
    float* out = (float*)d_out;

    uchar* wsb = (uchar*)d_ws;
    uchar* pre_s_t   = wsb + B_PRST;
    uchar* pre_tr_t  = wsb + B_PRTT;
    uchar* post_s_t  = wsb + B_POST;
    uchar* post_tr_t = wsb + B_POTT;
    float* Spart     = (float*)(wsb + B_END);

    stdp_traces_t<<<dim3(BATCH * (NIN + NOUT) / 64), dim3(256), 0, stream>>>(
        pre_s, post_s, pre_tr0, post_tr0,
        pre_s_t, pre_tr_t, post_s_t, post_tr_t, out);

    stdp_gemm_dual<<<dim3(NIN / 128, NOUT / 128, KS), dim3(256), 0, stream>>>(
        post_s_t, pre_tr_t, post_tr_t, pre_s_t, weight, Spart);

    stdp_finalize<<<dim3((NOUT * NIN / 4) / 256), dim3(256), 0, stream>>>(
        Spart, out);
}